// Round 10
// baseline (339.679 us; speedup 1.0000x reference)
//
#include <hip/hip_runtime.h>
#include <stdint.h>

typedef unsigned short u16;
typedef unsigned int   u32;

#define HW   16384      // 128*128
#define NPIX 131072     // 8 * HW

__device__ __forceinline__ float sigm(float x) { return 1.f / (1.f + __expf(-x)); }
__device__ __forceinline__ float rdlane(float v, int lane) {
    return __int_as_float(__builtin_amdgcn_readlane(__float_as_int(v), lane));
}

// R4..R9 post-mortem: six structures all pin at ~100-190us with 2 waves/SIMD
// (512-block grid invariant). R6 calibration: per-SIMD VALU busy ~19%, waves
// stalled ~80% on memory; intra-wave ILP attempts all defeated (allocator
// sinking R7/R8, barrier drain R9). R10 = the TLP experiment: R6's readlane
// matvec (fastest structure) + in-block split-K: 2048 blocks x 4 waves, block
// = 64 px, wave w covers channels [64w,64w+64). Per-wave chain 4x shorter,
// ~24 waves/CU (LDS 23KB, launch_bounds(256,6)). Partial-reduce via LDS;
// tail = R6-verbatim on wave 0. Decisive: latency-wall -> ~35-55us;
// DRAM-pattern-wall -> pinned ~110us.
__global__ __launch_bounds__(256, 6) void half_graph_fused(
    const float* __restrict__ hf,  const float* __restrict__ xhu, const float* __restrict__ xhl,
    const float* __restrict__ xfg, const float* __restrict__ xpg,
    const float* __restrict__ pdp_w1, const float* __restrict__ pdp_w2,
    const float* __restrict__ att_w,  const float* __restrict__ att_b,
    const float* __restrict__ cU_aw, const float* __restrict__ cU_ab, const float* __restrict__ cU_w,
    const float* __restrict__ cL_aw, const float* __restrict__ cL_ab, const float* __restrict__ cL_w,
    const float* __restrict__ dU_aw, const float* __restrict__ dU_ab, const float* __restrict__ dU_w,
    const float* __restrict__ dL_aw, const float* __restrict__ dL_ab, const float* __restrict__ dL_w,
    const float* __restrict__ uU_gw, const float* __restrict__ uU_gb, const float* __restrict__ uU_cw,
    const float* __restrict__ uL_gw, const float* __restrict__ uL_gb, const float* __restrict__ uL_cw,
    float* __restrict__ out)
{
    __shared__ float red[4][22][66];      // 23.2 KB: per-wave channel-chunk partials

    const int tid = threadIdx.x;
    const int wv  = tid >> 6;             // wave -> channel chunk [64wv, 64wv+64)
    const int ln  = tid & 63;             // lane -> pixel within block
    const int pb  = blockIdx.x;           // 2048 blocks, 64 px each
    const int n   = pb >> 8;              // batch
    const int hw  = ((pb & 255) << 6) + ln;

    // ---- per-wave weight prefetch: w[o] = W[o][64wv + ln] (22 coalesced loads) ----
    float w[22];
    #pragma unroll
    for (int o = 0; o < 20; ++o) w[o] = pdp_w1[o * 276 + wv * 64 + ln];
    w[20] = dU_aw[wv * 64 + ln];
    w[21] = dL_aw[wv * 64 + ln];

    // ---- matvec chunk: 64 channels, readlane weight broadcast ----
    float acc[22];
    #pragma unroll
    for (int o = 0; o < 22; ++o) acc[o] = 0.f;

    const float* xb = hf + ((size_t)n * 256 + wv * 64) * HW + hw;
    #pragma unroll 8
    for (int cc = 0; cc < 64; ++cc) {
        float x = xb[(size_t)cc * HW];    // 256B/wave coalesced
        #pragma unroll
        for (int o = 0; o < 22; ++o)
            acc[o] = fmaf(rdlane(w[o], cc), x, acc[o]);
    }

    #pragma unroll
    for (int o = 0; o < 22; ++o) red[wv][o][ln] = acc[o];
    __syncthreads();
    if (wv != 0) return;                  // tail: wave 0 only (64 px = 64 lanes)

    float accT[20];
    #pragma unroll
    for (int o = 0; o < 20; ++o)
        accT[o] = (red[0][o][ln] + red[1][o][ln]) + (red[2][o][ln] + red[3][o][ln]);
    const float dU = (red[0][20][ln] + red[1][20][ln]) + (red[2][20][ln] + red[3][20][ln]);
    const float dL = (red[0][21][ln] + red[1][21][ln]) + (red[2][21][ln] + red[3][21][ln]);

    // ================= tail (R6-verbatim math), 1 px/lane =================
    float xu[10], xl[10], xv[10];
    {
        const float* a = xhu + (size_t)n * 10 * HW + hw;
        const float* b = xhl + (size_t)n * 10 * HW + hw;
        const float* c = xfg + (size_t)n * 10 * HW + hw;
        #pragma unroll
        for (int i = 0; i < 10; ++i) xu[i] = a[i * HW];
        #pragma unroll
        for (int i = 0; i < 10; ++i) xl[i] = b[i * HW];
        #pragma unroll
        for (int i = 0; i < 10; ++i) xv[i] = c[i * HW];
    }

    // pdp: t = relu(W1 @ [hf,xu,xl])
    float t[20];
    #pragma unroll
    for (int o = 0; o < 20; ++o) {
        float s = accT[o];
        #pragma unroll
        for (int i = 0; i < 10; ++i) s = fmaf(pdp_w1[o * 276 + 256 + i], xu[i], s);
        #pragma unroll
        for (int i = 0; i < 10; ++i) s = fmaf(pdp_w1[o * 276 + 266 + i], xl[i], s);
        t[o] = fmaxf(s, 0.f);
    }
    float dpv[20];
    #pragma unroll
    for (int g = 0; g < 2; ++g) {
        #pragma unroll
        for (int o = 0; o < 10; ++o) {
            float s = 0.f;
            #pragma unroll
            for (int i = 0; i < 10; ++i)
                s = fmaf(pdp_w2[(g * 10 + o) * 10 + i], t[g * 10 + i], s);
            dpv[g * 10 + o] = fmaxf(s, 0.f);
        }
    }

    float au_s = att_b[0], al_s = att_b[1];
    #pragma unroll
    for (int i = 0; i < 10; ++i) {
        au_s = fmaf(att_w[i], xu[i], au_s);
        al_s = fmaf(att_w[10 + i], xl[i], al_s);
    }
    const float au = sigm(au_s), al = sigm(al_s);

    float su = dU + dU_ab[0];
    float sl = dL + dL_ab[0];
    #pragma unroll
    for (int i = 0; i < 10; ++i) { su = fmaf(dU_aw[256 + i], xv[i], su); sl = fmaf(dL_aw[256 + i], xv[i], sl); }
    #pragma unroll
    for (int i = 0; i < 10; ++i) { su = fmaf(dU_aw[266 + i], xu[i], su); sl = fmaf(dL_aw[266 + i], xl[i], sl); }
    const float attU = sigm(su), attL = sigm(sl);

    float xfhu[10], xfhl[10];
    #pragma unroll
    for (int o = 0; o < 10; ++o) {
        float a = 0.f, b = 0.f;
        #pragma unroll
        for (int i = 0; i < 10; ++i) {
            a = fmaf(dU_w[o * 10 + i], xv[i], a);
            b = fmaf(dL_w[o * 10 + i], xv[i], b);
        }
        xfhu[o] = fmaxf(attU * a, 0.f);
        xfhl[o] = fmaxf(attL * b, 0.f);
    }

    float msgU[10];
    #pragma unroll
    for (int i = 0; i < 10; ++i) msgU[i] = 0.f;
    #pragma unroll
    for (int pp = 0; pp < 4; ++pp) {
        const float* xq = xpg + (size_t)(pp * 8 + n) * 10 * HW + hw;
        float v[10];
        #pragma unroll
        for (int i = 0; i < 10; ++i) v[i] = xq[i * HW];
        float s = cU_ab[pp];
        #pragma unroll
        for (int i = 0; i < 10; ++i) s = fmaf(cU_aw[pp * 10 + i], v[i], s);
        float ca = sigm(s);
        #pragma unroll
        for (int i = 0; i < 10; ++i) msgU[i] = fmaf(ca, v[i], msgU[i]);
    }
    float xphu[10];
    #pragma unroll
    for (int o = 0; o < 10; ++o) {
        float s = 0.f;
        #pragma unroll
        for (int i = 0; i < 10; ++i) s = fmaf(cU_w[o * 20 + i], xu[i], s);
        #pragma unroll
        for (int i = 0; i < 10; ++i) s = fmaf(cU_w[o * 20 + 10 + i], msgU[i], s);
        xphu[o] = fmaxf(s, 0.f);
    }

    float msgL[10];
    #pragma unroll
    for (int i = 0; i < 10; ++i) msgL[i] = 0.f;
    #pragma unroll
    for (int pp = 4; pp < 6; ++pp) {
        const float* xq = xpg + (size_t)(pp * 8 + n) * 10 * HW + hw;
        float v[10];
        #pragma unroll
        for (int i = 0; i < 10; ++i) v[i] = xq[i * HW];
        float s = cL_ab[pp - 4];
        #pragma unroll
        for (int i = 0; i < 10; ++i) s = fmaf(cL_aw[(pp - 4) * 10 + i], v[i], s);
        float ca = sigm(s);
        #pragma unroll
        for (int i = 0; i < 10; ++i) msgL[i] = fmaf(ca, v[i], msgL[i]);
    }
    float xphl[10];
    #pragma unroll
    for (int o = 0; o < 10; ++o) {
        float s = 0.f;
        #pragma unroll
        for (int i = 0; i < 10; ++i) s = fmaf(cL_w[o * 20 + i], xl[i], s);
        #pragma unroll
        for (int i = 0; i < 10; ++i) s = fmaf(cL_w[o * 20 + 10 + i], msgL[i], s);
        xphl[o] = fmaxf(s, 0.f);
    }

    float outU[10], outL[10];
    {
        float m[10];
        #pragma unroll
        for (int i = 0; i < 10; ++i)
            m[i] = xphu[i] + (dpv[10 + i] * al + xu[i] * au) + xfhu[i];  // xlh
        #pragma unroll
        for (int o = 0; o < 10; ++o) {
            float gs = uU_gb[o], cs = 0.f;
            #pragma unroll
            for (int i = 0; i < 10; ++i) {
                gs = fmaf(uU_gw[o * 20 + i], xu[i], gs);
                cs = fmaf(uU_cw[o * 20 + i], xu[i], cs);
            }
            #pragma unroll
            for (int i = 0; i < 10; ++i) {
                gs = fmaf(uU_gw[o * 20 + 10 + i], m[i], gs);
                cs = fmaf(uU_cw[o * 20 + 10 + i], m[i], cs);
            }
            float g = sigm(gs), cd = fmaxf(cs, 0.f);
            outU[o] = xu[o] * (1.f - g) + cd * g;
        }
    }
    {
        float m[10];
        #pragma unroll
        for (int i = 0; i < 10; ++i)
            m[i] = xphl[i] + (dpv[i] * au + xl[i] * al) + xfhl[i];       // xuh
        #pragma unroll
        for (int o = 0; o < 10; ++o) {
            float gs = uL_gb[o], cs = 0.f;
            #pragma unroll
            for (int i = 0; i < 10; ++i) {
                gs = fmaf(uL_gw[o * 20 + i], xl[i], gs);
                cs = fmaf(uL_cw[o * 20 + i], xl[i], cs);
            }
            #pragma unroll
            for (int i = 0; i < 10; ++i) {
                gs = fmaf(uL_gw[o * 20 + 10 + i], m[i], gs);
                cs = fmaf(uL_cw[o * 20 + 10 + i], m[i], cs);
            }
            float g = sigm(gs), cd = fmaxf(cs, 0.f);
            outL[o] = xl[o] * (1.f - g) + cd * g;
        }
    }

    {
        int baseU = n * 10 * HW + hw;
        #pragma unroll
        for (int c = 0; c < 10; ++c) out[baseU + c * HW] = outU[c];
        int baseL = 1310720 + baseU;
        #pragma unroll
        for (int c = 0; c < 10; ++c) out[baseL + c * HW] = outL[c];
        out[2621440 + n * HW + hw] = attU;
        out[2752512 + n * HW + hw] = attL;
    }
}

extern "C" void kernel_launch(void* const* d_in, const int* in_sizes, int n_in,
                              void* d_out, int out_size, void* d_ws, size_t ws_size,
                              hipStream_t stream) {
    (void)in_sizes; (void)n_in; (void)out_size; (void)d_ws; (void)ws_size;
    const float* hf   = (const float*)d_in[0];
    const float* xhu  = (const float*)d_in[1];
    const float* xhl  = (const float*)d_in[2];
    const float* xfg  = (const float*)d_in[3];
    const float* xpg  = (const float*)d_in[4];
    const float* w1   = (const float*)d_in[5];
    const float* w2   = (const float*)d_in[6];
    const float* aw   = (const float*)d_in[7];
    const float* ab   = (const float*)d_in[8];
    const float* cUaw = (const float*)d_in[9];
    const float* cUab = (const float*)d_in[10];
    const float* cUw  = (const float*)d_in[11];
    const float* cLaw = (const float*)d_in[12];
    const float* cLab = (const float*)d_in[13];
    const float* cLw  = (const float*)d_in[14];
    const float* dUaw = (const float*)d_in[15];
    const float* dUab = (const float*)d_in[16];
    const float* dUw  = (const float*)d_in[17];
    const float* dLaw = (const float*)d_in[18];
    const float* dLab = (const float*)d_in[19];
    const float* dLw  = (const float*)d_in[20];
    const float* uUgw = (const float*)d_in[21];
    const float* uUgb = (const float*)d_in[22];
    const float* uUcw = (const float*)d_in[23];
    const float* uLgw = (const float*)d_in[24];
    const float* uLgb = (const float*)d_in[25];
    const float* uLcw = (const float*)d_in[26];

    dim3 grid(NPIX / 64), block(256);   // 2048 blocks: 64 px, 4 waves split over channels
    hipLaunchKernelGGL(half_graph_fused, grid, block, 0, stream,
        hf, xhu, xhl, xfg, xpg, w1, w2, aw, ab,
        cUaw, cUab, cUw, cLaw, cLab, cLw,
        dUaw, dUab, dUw, dLaw, dLab, dLw,
        uUgw, uUgb, uUcw, uLgw, uLgb, uLcw,
        (float*)d_out);
}